// Round 2
// baseline (296.980 us; speedup 1.0000x reference)
//
#include <hip/hip_runtime.h>

// HybridQuantumNetQML — round 2: occupancy + coalescing restructure.
//
// Block = 896 threads = 14 waves; lane = sample (64 samples/block).
// Wave w owns patch-row w (14 patches), processed as 7 steps of 2 patches:
// each step loads one float4 from image row 2w and one from row 2w+1
// (16 B/lane). Weight addresses are wave-uniform (wave id via
// readfirstlane) -> scalar loads. Partial acc[10] per (wave, sample)
// reduced through LDS (stride-11 padding: 2-way bank aliasing = free).
// Epilogue: 640 threads, one per (sample, class); log_softmax via a second
// LDS pass; output store fully coalesced (640 consecutive floats/block).
//
// Occupancy: 2 blocks/CU = 28 waves/CU (needs VGPR<=64 -> launch_bounds 7/EU).
// LDS: 14*704*4 + 320*4 + 704*4 = 43.5 KB/block -> 87 KB per 2 blocks < 160 KB.

#define NWAVES 14
#define BLOCKT (NWAVES * 64)

__global__ __launch_bounds__(BLOCKT, 7)
void qml_kernel(const float* __restrict__ x,
                const float* __restrict__ wm,     // (787, 10) row-major
                const float* __restrict__ bias,   // (10,)
                const float* __restrict__ sw,     // (4,)
                float* __restrict__ out,          // (B, 10)
                int B)
{
    __shared__ float red[NWAVES][64 * 11];  // [wave][sample*11 + c]
    __shared__ float qfs[64 * 5];           // patch-0 feats per sample (pad 5)
    __shared__ float lg[64 * 11];           // logits for log_softmax pass

    const int lane = threadIdx.x & 63;
    const int wv = __builtin_amdgcn_readfirstlane((int)(threadIdx.x >> 6));

    int sample = blockIdx.x * 64 + lane;
    const bool s_ok = (sample < B);
    if (sample >= B) sample = B - 1;        // clamp loads; stores guarded

    const float* __restrict__ xrow = x + (size_t)sample * 784;

    float acc[10];
#pragma unroll
    for (int c = 0; c < 10; ++c) acc[c] = 0.0f;

    // wave w: image rows 2w, 2w+1 start at float offset 56*w; weight rows
    // for patch p = 14w + 2k start at (56w + 8k)*10.
    const int rowoff = 56 * wv;
    const float* __restrict__ wbase = wm + (size_t)rowoff * 10;

    float qf0 = 0.f, qf1 = 0.f, qf2 = 0.f, qf3 = 0.f;

#pragma unroll
    for (int k = 0; k < 7; ++k) {
        const float4 top = *(const float4*)(xrow + rowoff + 4 * k);
        const float4 bot = *(const float4*)(xrow + rowoff + 28 + 4 * k);

        // patch A = (row wv, col 2k), patch B = (row wv, col 2k+1)
        const float ca = __cosf(top.x), cb = __cosf(top.y);
        const float cc = __cosf(bot.x), cd = __cosf(bot.y);
        const float vA0 = ca, vA1 = ca * cb, vA2 = cc, vA3 = cc * cd;

        const float ce = __cosf(top.z), cf = __cosf(top.w);
        const float cg = __cosf(bot.z), ch = __cosf(bot.w);
        const float vB0 = ce, vB1 = ce * cf, vB2 = cg, vB3 = cg * ch;

        if (wv == 0 && k == 0) { qf0 = vA0; qf1 = vA1; qf2 = vA2; qf3 = vA3; }

        const float* __restrict__ wr = wbase + 80 * k;  // uniform -> s_load
#pragma unroll
        for (int c = 0; c < 10; ++c) {
            acc[c] += vA0 * wr[c]      + vA1 * wr[10 + c]
                    + vA2 * wr[20 + c] + vA3 * wr[30 + c]
                    + vB0 * wr[40 + c] + vB1 * wr[50 + c]
                    + vB2 * wr[60 + c] + vB3 * wr[70 + c];
        }
    }

#pragma unroll
    for (int c = 0; c < 10; ++c) red[wv][lane * 11 + c] = acc[c];
    if (wv == 0) {
        qfs[lane * 5 + 0] = qf0; qfs[lane * 5 + 1] = qf1;
        qfs[lane * 5 + 2] = qf2; qfs[lane * 5 + 3] = qf3;
    }
    __syncthreads();

    const int t = threadIdx.x;
    const int s = t / 10;          // sample within block
    const int c = t - 10 * s;      // class
    float logit = 0.0f;

    if (t < 640) {
        float sum = 0.0f;
#pragma unroll
        for (int w2 = 0; w2 < NWAVES; ++w2) sum += red[w2][s * 11 + c];

        const float q0 = qfs[s * 5 + 0], q1 = qfs[s * 5 + 1];
        const float q2 = qfs[s * 5 + 2], q3 = qfs[s * 5 + 3];

        // qfc
        const float f0 = __cosf(q0), f1 = __cosf(q1);
        const float f2 = __cosf(q2), f3 = __cosf(q3);
        const float qfc = (f0 + f0 * f1 + f2 + f2 * f3) * 0.25f;

        // sampler softmax
        const float t0 = q0 + sw[0] + sw[2];
        const float t1 = q1 + sw[1] + sw[3];
        const float z0 = __cosf(t0);
        const float z1 = z0 * __cosf(t1);
        const float e0 = __expf(z0);
        const float e1 = __expf(z1);
        const float inv = 1.0f / (e0 + e1);
        const float s0 = e0 * inv, s1 = e1 * inv;

        const float* __restrict__ wt = wm + 7840;  // rows 784..786
        logit = sum + bias[c] + qfc * wt[c] + s0 * wt[10 + c] + s1 * wt[20 + c];
        lg[s * 11 + c] = logit;
    }
    __syncthreads();

    if (t < 640) {
        float m = -3.4e38f;
#pragma unroll
        for (int k2 = 0; k2 < 10; ++k2) m = fmaxf(m, lg[s * 11 + k2]);
        float ssum = 0.0f;
#pragma unroll
        for (int k2 = 0; k2 < 10; ++k2) ssum += __expf(lg[s * 11 + k2] - m);
        const float lse = __logf(ssum) + m;

        if (blockIdx.x * 64 + s < B)
            out[(size_t)blockIdx.x * 640 + t] = logit - lse;
    }
}

extern "C" void kernel_launch(void* const* d_in, const int* in_sizes, int n_in,
                              void* d_out, int out_size, void* d_ws, size_t ws_size,
                              hipStream_t stream) {
    const float* x    = (const float*)d_in[0];   // (B,1,28,28) f32
    const float* w    = (const float*)d_in[1];   // (787,10)    f32
    const float* bias = (const float*)d_in[2];   // (10,)       f32
    const float* sw   = (const float*)d_in[3];   // (4,)        f32
    float* out = (float*)d_out;                  // (B,10)      f32

    const int B = in_sizes[0] / 784;
    const int blocks = (B + 63) / 64;
    qml_kernel<<<blocks, BLOCKT, 0, stream>>>(x, w, bias, sw, out, B);
}

// Round 3
// 181.842 us; speedup vs baseline: 1.6332x; 1.6332x over previous
//
#include <hip/hip_runtime.h>

// HybridQuantumNetQML — round 3: split-patch two-kernel design.
//
// Round 1 (62 us) was latency-bound at 8 waves/CU (grid-limited: 512 blocks
// x 4 waves). Round 2's big-block fix caused ~600 B/thread scratch spill
// (WRITE_SIZE 277 MB). Round 3 keeps round 1's clean low-VGPR inner loop and
// gets occupancy from MORE blocks: grid = (B/64) x 7 patch strips.
//
// K1: block = 256 thr = 4 waves, 64 samples (one/lane). Block (g, ps) covers
//     image rows 4ps..4ps+3; wave w handles 7 consecutive patches
//     (patch row i = 2ps + (w>>1), cols 7*(w&1)..+6). Weight addresses are
//     wave-uniform -> s_load. 4-wave LDS reduce -> partial[10]/sample ->
//     workspace. Strip 0 / wave 0 also records qfeat[0:4] per sample.
//     14336 waves total -> 32 waves/CU (LDS 8.4 KB -> 8 blocks/CU).
// K2: 512 blocks x 640 thr; thread (s,c) sums 7 partials (coalesced),
//     adds qfc/sampler/tail rows + bias, log_softmax via LDS, stores out.

__global__ __launch_bounds__(256, 8)
void qml_k1(const float* __restrict__ x,
            const float* __restrict__ wm,     // (787,10)
            float* __restrict__ part,         // (7, nblk, 640)
            float* __restrict__ qf,           // (B, 4)
            int B, int nblk)
{
    __shared__ float red[3][64 * 11];

    const int lane = threadIdx.x & 63;
    const int wv = __builtin_amdgcn_readfirstlane((int)(threadIdx.x >> 6));
    const int g = blockIdx.x;
    const int ps = blockIdx.y;

    int sample = g * 64 + lane;
    const bool s_ok = (sample < B);
    if (sample >= B) sample = B - 1;          // clamp loads; stores guarded
    const float* __restrict__ xrow = x + (size_t)sample * 784;

    const int i = 2 * ps + (wv >> 1);         // patch row
    const int j = 7 * (wv & 1);               // first patch col (0 or 7)
    const int p0 = i * 14 + j;                // first patch index
    const int xoff = i * 56 + 2 * j;          // float offset of (row 2i, col 2j)

    float acc[10];
#pragma unroll
    for (int c = 0; c < 10; ++c) acc[c] = 0.0f;

    float q0 = 0.f, q1 = 0.f, q2 = 0.f, q3 = 0.f;

#pragma unroll
    for (int t = 0; t < 7; ++t) {
        const float2 a01 = *(const float2*)(xrow + xoff + 2 * t);       // row 2i
        const float2 a23 = *(const float2*)(xrow + xoff + 28 + 2 * t);  // row 2i+1

        const float c0 = __cosf(a01.x);
        const float c1 = __cosf(a01.y);
        const float c2 = __cosf(a23.x);
        const float c3 = __cosf(a23.y);
        const float v0 = c0;
        const float v1 = c0 * c1;
        const float v2 = c2;
        const float v3 = c2 * c3;

        if (t == 0 && ps == 0 && wv == 0) { q0 = v0; q1 = v1; q2 = v2; q3 = v3; }

        const float* __restrict__ wr = wm + 40 * (p0 + t);   // uniform -> s_load
#pragma unroll
        for (int c = 0; c < 10; ++c)
            acc[c] += v0 * wr[c] + v1 * wr[10 + c] + v2 * wr[20 + c] + v3 * wr[30 + c];
    }

    if (ps == 0 && wv == 0 && s_ok) {
        float* __restrict__ qd = qf + 4 * (size_t)sample;
        qd[0] = q0; qd[1] = q1; qd[2] = q2; qd[3] = q3;
    }

    if (wv != 0) {
#pragma unroll
        for (int c = 0; c < 10; ++c) red[wv - 1][lane * 11 + c] = acc[c];
    }
    __syncthreads();

    if (wv == 0) {
        float* __restrict__ dst = part + ((size_t)(ps * nblk + g)) * 640 + lane * 10;
#pragma unroll
        for (int c = 0; c < 10; ++c)
            dst[c] = acc[c] + red[0][lane * 11 + c] + red[1][lane * 11 + c]
                            + red[2][lane * 11 + c];
    }
}

__global__ __launch_bounds__(640, 1)
void qml_k2(const float* __restrict__ part,   // (7, nblk, 640)
            const float* __restrict__ qf,     // (B, 4)
            const float* __restrict__ wm,     // (787,10)
            const float* __restrict__ bias,   // (10,)
            const float* __restrict__ sw,     // (4,)
            float* __restrict__ out,          // (B,10)
            int B, int nblk)
{
    __shared__ float lg[64 * 11];

    const int t = threadIdx.x;                // 0..639
    const int g = blockIdx.x;
    const int s = t / 10;
    const int c = t - 10 * s;

    float sum = 0.0f;
#pragma unroll
    for (int ps = 0; ps < 7; ++ps)
        sum += part[((size_t)(ps * nblk + g)) * 640 + t];   // coalesced

    int sample = g * 64 + s;
    const bool ok = (sample < B);
    if (sample >= B) sample = B - 1;

    const float* __restrict__ qr = qf + 4 * (size_t)sample;
    const float q0 = qr[0], q1 = qr[1], q2 = qr[2], q3 = qr[3];

    // qfc
    const float f0 = __cosf(q0), f1 = __cosf(q1);
    const float f2 = __cosf(q2), f3 = __cosf(q3);
    const float qfc = (f0 + f0 * f1 + f2 + f2 * f3) * 0.25f;

    // sampler softmax
    const float t0 = q0 + sw[0] + sw[2];
    const float t1 = q1 + sw[1] + sw[3];
    const float z0 = __cosf(t0);
    const float z1 = z0 * __cosf(t1);
    const float e0 = __expf(z0);
    const float e1 = __expf(z1);
    const float inv = 1.0f / (e0 + e1);
    const float s0 = e0 * inv, s1 = e1 * inv;

    const float* __restrict__ wt = wm + 7840;   // rows 784..786 (uniform)
    const float logit = sum + bias[c] + qfc * wt[c] + s0 * wt[10 + c] + s1 * wt[20 + c];
    lg[s * 11 + c] = logit;
    __syncthreads();

    float m = -3.4e38f;
#pragma unroll
    for (int k = 0; k < 10; ++k) m = fmaxf(m, lg[s * 11 + k]);
    float ssum = 0.0f;
#pragma unroll
    for (int k = 0; k < 10; ++k) ssum += __expf(lg[s * 11 + k] - m);
    const float lse = __logf(ssum) + m;

    if (ok) out[(size_t)g * 640 + t] = logit - lse;
}

extern "C" void kernel_launch(void* const* d_in, const int* in_sizes, int n_in,
                              void* d_out, int out_size, void* d_ws, size_t ws_size,
                              hipStream_t stream) {
    const float* x    = (const float*)d_in[0];   // (B,1,28,28) f32
    const float* w    = (const float*)d_in[1];   // (787,10)    f32
    const float* bias = (const float*)d_in[2];   // (10,)       f32
    const float* sw   = (const float*)d_in[3];   // (4,)        f32
    float* out = (float*)d_out;                  // (B,10)      f32

    const int B = in_sizes[0] / 784;
    const int nblk = (B + 63) / 64;

    float* part = (float*)d_ws;                          // 7*nblk*640 floats
    float* qf   = part + (size_t)7 * nblk * 640;         // B*4 floats

    dim3 grid1(nblk, 7);
    qml_k1<<<grid1, 256, 0, stream>>>(x, w, part, qf, B, nblk);
    qml_k2<<<nblk, 640, 0, stream>>>(part, qf, w, bias, sw, out, B, nblk);
}

// Round 4
// 164.962 us; speedup vs baseline: 1.8003x; 1.1023x over previous
//
#include <hip/hip_runtime.h>

// HybridQuantumNetQML — round 4: coalesced LDS-staged split-K.
//
// R1/R3 evidence: lane=sample direct loads are cacheline-transaction-bound
// (64 lines per wave-load; 60-77us regardless of occupancy). Fix: stage each
// block's 64x112-float strip into LDS with coalesced float4 loads, compute
// from LDS (XOR-swizzled rows, float2-preserving), store partials coalesced.
//
// K1: grid (nblk, 7), block 256 = 4 waves. Block (g,ps) covers image rows
//     4ps..4ps+3 (patch rows 2ps, 2ps+1). Wave wv: patch row 2ps+(wv>>1),
//     cols 7*(wv&1)..+6. acc[10]/lane; 4-wave LDS reduce (buffer aliased
//     over staging area); partials stored as (ps,g,c,lane) full-line runs.
// K2: nblk blocks x 640 thr; thread (c=t>>6, s=t&63) sums 7 partials
//     (contiguous), adds qfc/sampler/tail+bias, log_softmax via LDS, store.

__global__ __launch_bounds__(256, 5)
void qml_k1(const float* __restrict__ x,
            const float* __restrict__ wm,     // (787,10)
            float* __restrict__ part,         // (7, nblk, 10, 64)
            float* __restrict__ qf,           // (4, B)
            int B, int nblk)
{
    __shared__ float lds[64 * 128];           // 32 KB: staging, then reduce

    const int t = threadIdx.x;
    const int lane = t & 63;
    const int wv = __builtin_amdgcn_readfirstlane((int)(t >> 6));
    const int g = blockIdx.x;
    const int ps = blockIdx.y;

    // ---- coalesced stage: sample s floats [ps*112, ps*112+112) ----
    // chunk f = k*256+t: s = f/28, c = f%28 (28 float4-chunks per sample).
    // LDS: float o of sample s at  s*128 + (o ^ (2*(s&15)))  [rows padded 128]
    {
        const int base_s = g * 64;
#pragma unroll
        for (int k = 0; k < 7; ++k) {
            const int f = k * 256 + t;
            const int s = f / 28;
            const int c = f - 28 * s;
            int sg = base_s + s; if (sg >= B) sg = B - 1;
            const float4 v = *(const float4*)(x + (size_t)sg * 784 + ps * 112 + 4 * c);
            const int m2 = (s & 15) << 1;
            float* __restrict__ d0 = lds + s * 128 + ((4 * c) ^ m2);
            float* __restrict__ d1 = lds + s * 128 + ((4 * c + 2) ^ m2);
            *(float2*)d0 = make_float2(v.x, v.y);
            *(float2*)d1 = make_float2(v.z, v.w);
        }
    }
    __syncthreads();

    // ---- compute from LDS ----
    const int i_loc = wv >> 1;                 // patch row within strip (0/1)
    const int jbase = 7 * (wv & 1);            // first patch col (0/7)
    const int o_top = i_loc * 56 + 2 * jbase;  // local float offset, row 2*i_loc
    const int p0 = (2 * ps + i_loc) * 14 + jbase;
    const int m2 = (lane & 15) << 1;
    const float* __restrict__ row = lds + lane * 128;

    float acc[10];
#pragma unroll
    for (int c = 0; c < 10; ++c) acc[c] = 0.0f;
    float q0 = 0.f, q1 = 0.f, q2 = 0.f, q3 = 0.f;

#pragma unroll
    for (int tt = 0; tt < 7; ++tt) {
        const int ot = o_top + 2 * tt;
        const float2 a = *(const float2*)(row + (ot ^ m2));          // row 2i
        const float2 b = *(const float2*)(row + ((ot + 28) ^ m2));   // row 2i+1

        const float c0 = __cosf(a.x);
        const float c1 = __cosf(a.y);
        const float c2 = __cosf(b.x);
        const float c3 = __cosf(b.y);
        const float v0 = c0, v1 = c0 * c1, v2 = c2, v3 = c2 * c3;

        if (ps == 0 && wv == 0 && tt == 0) { q0 = v0; q1 = v1; q2 = v2; q3 = v3; }

        const float* __restrict__ wr = wm + 40 * (p0 + tt);   // uniform -> s_load
#pragma unroll
        for (int c = 0; c < 10; ++c)
            acc[c] += v0 * wr[c] + v1 * wr[10 + c] + v2 * wr[20 + c] + v3 * wr[30 + c];
    }

    __syncthreads();   // staging data dead; reuse lds as reduce buffer

    if (wv != 0) {
#pragma unroll
        for (int c = 0; c < 10; ++c) lds[(wv - 1) * 704 + lane * 11 + c] = acc[c];
    }
    __syncthreads();

    if (wv == 0) {
#pragma unroll
        for (int c = 0; c < 10; ++c)
            acc[c] += lds[lane * 11 + c] + lds[704 + lane * 11 + c]
                    + lds[1408 + lane * 11 + c];

        // coalesced partial store: 10 x contiguous 256 B (full lines)
        float* __restrict__ dst = part + (size_t)(ps * nblk + g) * 640;
#pragma unroll
        for (int c = 0; c < 10; ++c) dst[c * 64 + lane] = acc[c];

        if (ps == 0) {
            const int sample = g * 64 + lane;
            if (sample < B) {
                qf[0 * (size_t)B + sample] = q0;
                qf[1 * (size_t)B + sample] = q1;
                qf[2 * (size_t)B + sample] = q2;
                qf[3 * (size_t)B + sample] = q3;
            }
        }
    }
}

__global__ __launch_bounds__(640, 1)
void qml_k2(const float* __restrict__ part,   // (7, nblk, 10, 64)
            const float* __restrict__ qf,     // (4, B)
            const float* __restrict__ wm,
            const float* __restrict__ bias,
            const float* __restrict__ sw,
            float* __restrict__ out,          // (B,10)
            int B, int nblk)
{
    __shared__ float lg[64 * 11];

    const int t = threadIdx.x;    // 0..639
    const int g = blockIdx.x;
    const int c = t >> 6;         // 0..9
    const int s = t & 63;

    float sum = 0.0f;
#pragma unroll
    for (int ps = 0; ps < 7; ++ps)
        sum += part[(size_t)(ps * nblk + g) * 640 + c * 64 + s];   // contiguous

    int sample = g * 64 + s;
    const bool ok = (sample < B);
    if (sample >= B) sample = B - 1;

    const float q0 = qf[0 * (size_t)B + sample];
    const float q1 = qf[1 * (size_t)B + sample];
    const float q2 = qf[2 * (size_t)B + sample];
    const float q3 = qf[3 * (size_t)B + sample];

    const float f0 = __cosf(q0), f1 = __cosf(q1);
    const float f2 = __cosf(q2), f3 = __cosf(q3);
    const float qfc = (f0 + f0 * f1 + f2 + f2 * f3) * 0.25f;

    const float t0 = q0 + sw[0] + sw[2];
    const float t1 = q1 + sw[1] + sw[3];
    const float z0 = __cosf(t0);
    const float z1 = z0 * __cosf(t1);
    const float e0 = __expf(z0);
    const float e1 = __expf(z1);
    const float inv = 1.0f / (e0 + e1);
    const float s0 = e0 * inv, s1 = e1 * inv;

    const float* __restrict__ wt = wm + 7840;
    const float logit = sum + bias[c] + qfc * wt[c] + s0 * wt[10 + c] + s1 * wt[20 + c];
    lg[s * 11 + c] = logit;
    __syncthreads();

    const int s2 = t / 10;
    const int c2 = t - 10 * s2;
    float m = -3.4e38f;
#pragma unroll
    for (int k = 0; k < 10; ++k) m = fmaxf(m, lg[s2 * 11 + k]);
    float ssum = 0.0f;
#pragma unroll
    for (int k = 0; k < 10; ++k) ssum += __expf(lg[s2 * 11 + k] - m);
    const float lse = __logf(ssum) + m;

    if (g * 64 + s2 < B)
        out[(size_t)g * 640 + t] = lg[s2 * 11 + c2] - lse;
}

extern "C" void kernel_launch(void* const* d_in, const int* in_sizes, int n_in,
                              void* d_out, int out_size, void* d_ws, size_t ws_size,
                              hipStream_t stream) {
    const float* x    = (const float*)d_in[0];   // (B,1,28,28) f32
    const float* w    = (const float*)d_in[1];   // (787,10)    f32
    const float* bias = (const float*)d_in[2];   // (10,)       f32
    const float* sw   = (const float*)d_in[3];   // (4,)        f32
    float* out = (float*)d_out;                  // (B,10)      f32

    const int B = in_sizes[0] / 784;
    const int nblk = (B + 63) / 64;

    float* part = (float*)d_ws;                          // 7*nblk*640 floats
    float* qf   = part + (size_t)7 * nblk * 640;         // 4*B floats

    dim3 grid1(nblk, 7);
    qml_k1<<<grid1, 256, 0, stream>>>(x, w, part, qf, B, nblk);
    qml_k2<<<nblk, 640, 0, stream>>>(part, qf, w, bias, sw, out, B, nblk);
}